// Round 2
// baseline (585.487 us; speedup 1.0000x reference)
//
#include <hip/hip_runtime.h>

#define EDGES_PER_TILE 32
#define THREADS 256

// One block = 4 waves, 32 edges/tile. Lane o owns output channel o and holds
// W[o][0..63] in 16 float4 VGPRs. Edge features staged in LDS, read back as
// same-address broadcasts (conflict-free). One fp32 HW atomic per lane per
// edge -> 64 consecutive floats per edge.
__global__ __launch_bounds__(THREADS)
void edge_agg_kernel(const float* __restrict__ edge_features,
                     const int* __restrict__ row_idx,
                     const float* __restrict__ W,
                     float* __restrict__ out,
                     int E)
{
    __shared__ float xs[EDGES_PER_TILE * 64];

    const int lane = threadIdx.x & 63;
    const int wave = threadIdx.x >> 6;   // 0..3

    // --- W row for this lane's output channel -> 64 VGPRs (once) ---
    float4 w[16];
    const float4* wsrc = reinterpret_cast<const float4*>(W + lane * 64);
#pragma unroll
    for (int i = 0; i < 16; ++i) w[i] = wsrc[i];

    const int tile_base = blockIdx.x * EDGES_PER_TILE;
    if (tile_base >= E) return;

    // --- cooperative stage: 32 edges x 64 floats = 512 float4 ---
    const float4* gsrc =
        reinterpret_cast<const float4*>(edge_features + (size_t)tile_base * 64);
    float4* ldst = reinterpret_cast<float4*>(xs);
    const int lim4 = (E - tile_base) * 16;   // float4s available in this tile
#pragma unroll
    for (int i = 0; i < 2; ++i) {
        int idx = threadIdx.x + i * THREADS;   // 0..511
        if (idx < lim4) ldst[idx] = gsrc[idx];
    }
    __syncthreads();

    // --- each wave handles 8 edges of the tile ---
#pragma unroll
    for (int i = 0; i < 8; ++i) {
        const int e_local = wave * 8 + i;
        const int e = tile_base + e_local;
        if (e >= E) break;

        const int r = row_idx[e];       // hoisted: overlaps the FMA chain

        const float4* xv = reinterpret_cast<const float4*>(xs + e_local * 64);
        float a0 = 0.f, a1 = 0.f, a2 = 0.f, a3 = 0.f;
#pragma unroll
        for (int c4 = 0; c4 < 16; ++c4) {
            float4 x = xv[c4];          // broadcast ds_read_b128
            a0 = fmaf(x.x, w[c4].x, a0);
            a1 = fmaf(x.y, w[c4].y, a1);
            a2 = fmaf(x.z, w[c4].z, a2);
            a3 = fmaf(x.w, w[c4].w, a3);
        }
        const float acc = (a0 + a1) + (a2 + a3);

        unsafeAtomicAdd(&out[(size_t)r * 64 + lane], acc);
    }
}

extern "C" void kernel_launch(void* const* d_in, const int* in_sizes, int n_in,
                              void* d_out, int out_size, void* d_ws, size_t ws_size,
                              hipStream_t stream) {
    const float* edge_features = (const float*)d_in[0];
    const int*   edge_index    = (const int*)d_in[1];   // [2, E] int32
    const float* W             = (const float*)d_in[3]; // [64, 64]
    float* out = (float*)d_out;

    const int E = in_sizes[1] / 2;                 // 1,000,000
    const int* row_idx = edge_index;               // edge_index[0] = first E

    // d_out is re-poisoned 0xAA before every timed call -> zero it here.
    hipMemsetAsync(d_out, 0, (size_t)out_size * sizeof(float), stream);

    const int blocks = (E + EDGES_PER_TILE - 1) / EDGES_PER_TILE;
    edge_agg_kernel<<<blocks, THREADS, 0, stream>>>(edge_features, row_idx, W,
                                                    out, E);
}

// Round 3
// 488.503 us; speedup vs baseline: 1.1985x; 1.1985x over previous
//
#include <hip/hip_runtime.h>

#define THREADS 256

// K1: scatter-add RAW edge features into node buckets (exploits linearity:
// segment_sum(X @ W^T) == segment_sum(X) @ W^T). Lane = channel, so each
// wave-level atomic hits 64 consecutive floats (4 cache lines).
__global__ __launch_bounds__(THREADS)
void scatter_accum_kernel(const float* __restrict__ X,
                          const int* __restrict__ row_idx,
                          float* __restrict__ acc,
                          int E)
{
    const int lane   = threadIdx.x & 63;
    const int wave_g = blockIdx.x * (THREADS / 64) + (threadIdx.x >> 6);
    const int nwaves = gridDim.x * (THREADS / 64);

    const int chunk = (E + nwaves - 1) / nwaves;   // contiguous range per wave
    const int e0 = wave_g * chunk;
    const int e1 = min(e0 + chunk, E);

    int e = e0;
    for (; e + 3 < e1; e += 4) {                   // unroll-4 for MLP/ILP
        float v0 = X[(size_t)(e + 0) * 64 + lane];
        float v1 = X[(size_t)(e + 1) * 64 + lane];
        float v2 = X[(size_t)(e + 2) * 64 + lane];
        float v3 = X[(size_t)(e + 3) * 64 + lane];
        int r0 = row_idx[e + 0];
        int r1 = row_idx[e + 1];
        int r2 = row_idx[e + 2];
        int r3 = row_idx[e + 3];
        unsafeAtomicAdd(&acc[(size_t)r0 * 64 + lane], v0);
        unsafeAtomicAdd(&acc[(size_t)r1 * 64 + lane], v1);
        unsafeAtomicAdd(&acc[(size_t)r2 * 64 + lane], v2);
        unsafeAtomicAdd(&acc[(size_t)r3 * 64 + lane], v3);
    }
    for (; e < e1; ++e) {
        float v = X[(size_t)e * 64 + lane];
        int r = row_idx[e];
        unsafeAtomicAdd(&acc[(size_t)r * 64 + lane], v);
    }
}

// K2: in-place projection nodes = nodes @ W^T on the [N,64] accumulator.
// Block stages 32 rows to LDS (all reads before any write -> in-place safe),
// lane = output channel holding W[lane][:] in 16 float4 VGPRs.
__global__ __launch_bounds__(THREADS)
void project_inplace_kernel(float* __restrict__ nodes,
                            const float* __restrict__ W,
                            int N)
{
    __shared__ float xs[32 * 64];
    const int lane = threadIdx.x & 63;
    const int wave = threadIdx.x >> 6;

    float4 w[16];
    const float4* wsrc = reinterpret_cast<const float4*>(W + lane * 64);
#pragma unroll
    for (int i = 0; i < 16; ++i) w[i] = wsrc[i];

    const int tile = blockIdx.x * 32;
    if (tile >= N) return;

    const float4* gsrc = reinterpret_cast<const float4*>(nodes + (size_t)tile * 64);
    float4* ldst = reinterpret_cast<float4*>(xs);
    const int lim4 = (N - tile) * 16;
#pragma unroll
    for (int i = 0; i < 2; ++i) {
        int idx = threadIdx.x + i * THREADS;
        if (idx < lim4) ldst[idx] = gsrc[idx];
    }
    __syncthreads();

#pragma unroll
    for (int i = 0; i < 8; ++i) {
        const int rl = wave * 8 + i;
        const int r = tile + rl;
        if (r >= N) break;

        const float4* xv = reinterpret_cast<const float4*>(xs + rl * 64);
        float a0 = 0.f, a1 = 0.f, a2 = 0.f, a3 = 0.f;
#pragma unroll
        for (int c4 = 0; c4 < 16; ++c4) {
            float4 x = xv[c4];
            a0 = fmaf(x.x, w[c4].x, a0);
            a1 = fmaf(x.y, w[c4].y, a1);
            a2 = fmaf(x.z, w[c4].z, a2);
            a3 = fmaf(x.w, w[c4].w, a3);
        }
        nodes[(size_t)r * 64 + lane] = (a0 + a1) + (a2 + a3);
    }
}

extern "C" void kernel_launch(void* const* d_in, const int* in_sizes, int n_in,
                              void* d_out, int out_size, void* d_ws, size_t ws_size,
                              hipStream_t stream) {
    const float* edge_features = (const float*)d_in[0];
    const int*   edge_index    = (const int*)d_in[1];   // [2, E] int32
    const float* W             = (const float*)d_in[3]; // [64, 64]
    float* out = (float*)d_out;

    const int E = in_sizes[1] / 2;                 // 1,000,000
    const int N = out_size / 64;                   // 50,000 nodes
    const int* row_idx = edge_index;               // edge_index[0]

    // d_out is re-poisoned 0xAA before every timed call -> zero it here.
    hipMemsetAsync(d_out, 0, (size_t)out_size * sizeof(float), stream);

    // K1: raw scatter-add (streaming + coalesced atomics)
    scatter_accum_kernel<<<2048, THREADS, 0, stream>>>(edge_features, row_idx,
                                                       out, E);
    // K2: in-place projection of the [N,64] node sums
    const int blocks2 = (N + 31) / 32;
    project_inplace_kernel<<<blocks2, THREADS, 0, stream>>>(out, W, N);
}

// Round 5
// 467.521 us; speedup vs baseline: 1.2523x; 1.0449x over previous
//
#include <hip/hip_runtime.h>

#define THREADS 256
#define CAP 64   // bucket capacity per node (max expected count ~41 for Poisson(20))

// --- K_bin: bucket edges by destination node (int atomics only) ---
__global__ __launch_bounds__(THREADS)
void bin_kernel(const int* __restrict__ row_idx,
                int* __restrict__ cnt,
                int* __restrict__ ids,
                const float* __restrict__ X,
                float* __restrict__ out,
                int E)
{
    int e = blockIdx.x * THREADS + threadIdx.x;
    if (e >= E) return;
    int r = row_idx[e];
    int pos = atomicAdd(&cnt[r], 1);
    if (pos < CAP) {
        ids[(size_t)r * CAP + pos] = e;
    } else {
        // overflow fallback (statistically never for this data; keeps correctness)
        for (int c = 0; c < 64; ++c)
            unsafeAtomicAdd(&out[(size_t)r * 64 + c], X[(size_t)e * 64 + c]);
    }
}

// --- K_gather: one wave per node, lane = channel, plain streaming reads ---
__global__ __launch_bounds__(THREADS)
void gather_kernel(const float* __restrict__ X,
                   const int* __restrict__ ids,
                   const int* __restrict__ cnt,
                   float* __restrict__ out,
                   int N)
{
    const int lane = threadIdx.x & 63;
    const int node = blockIdx.x * (THREADS / 64) + (threadIdx.x >> 6);
    if (node >= N) return;

    const int n = min(cnt[node], CAP);
    const int* myids = ids + (size_t)node * CAP;

    // start from existing value (0, or overflow contributions in the rare case)
    float acc = out[(size_t)node * 64 + lane];

    int i = 0;
    for (; i + 3 < n; i += 4) {            // 4 loads in flight for latency hiding
        int e0 = myids[i + 0];
        int e1 = myids[i + 1];
        int e2 = myids[i + 2];
        int e3 = myids[i + 3];
        float v0 = X[(size_t)e0 * 64 + lane];
        float v1 = X[(size_t)e1 * 64 + lane];
        float v2 = X[(size_t)e2 * 64 + lane];
        float v3 = X[(size_t)e3 * 64 + lane];
        acc += (v0 + v1) + (v2 + v3);
    }
    for (; i < n; ++i)
        acc += X[(size_t)myids[i] * 64 + lane];

    out[(size_t)node * 64 + lane] = acc;
}

// --- K_proj: in-place projection nodes = nodes @ W^T (unchanged from R3) ---
__global__ __launch_bounds__(THREADS)
void project_inplace_kernel(float* __restrict__ nodes,
                            const float* __restrict__ W,
                            int N)
{
    __shared__ float xs[32 * 64];
    const int lane = threadIdx.x & 63;
    const int wave = threadIdx.x >> 6;

    float4 w[16];
    const float4* wsrc = reinterpret_cast<const float4*>(W + lane * 64);
#pragma unroll
    for (int i = 0; i < 16; ++i) w[i] = wsrc[i];

    const int tile = blockIdx.x * 32;
    if (tile >= N) return;

    const float4* gsrc = reinterpret_cast<const float4*>(nodes + (size_t)tile * 64);
    float4* ldst = reinterpret_cast<float4*>(xs);
    const int lim4 = (N - tile) * 16;
#pragma unroll
    for (int i = 0; i < 2; ++i) {
        int idx = threadIdx.x + i * THREADS;
        if (idx < lim4) ldst[idx] = gsrc[idx];
    }
    __syncthreads();

#pragma unroll
    for (int i = 0; i < 8; ++i) {
        const int rl = wave * 8 + i;
        const int r = tile + rl;
        if (r >= N) break;

        const float4* xv = reinterpret_cast<const float4*>(xs + rl * 64);
        float a0 = 0.f, a1 = 0.f, a2 = 0.f, a3 = 0.f;
#pragma unroll
        for (int c4 = 0; c4 < 16; ++c4) {
            float4 x = xv[c4];
            a0 = fmaf(x.x, w[c4].x, a0);
            a1 = fmaf(x.y, w[c4].y, a1);
            a2 = fmaf(x.z, w[c4].z, a2);
            a3 = fmaf(x.w, w[c4].w, a3);
        }
        nodes[(size_t)r * 64 + lane] = (a0 + a1) + (a2 + a3);
    }
}

// --- fallback (round-3 path) if d_ws is too small for the buckets ---
__global__ __launch_bounds__(THREADS)
void scatter_accum_kernel(const float* __restrict__ X,
                          const int* __restrict__ row_idx,
                          float* __restrict__ acc,
                          int E)
{
    const int lane   = threadIdx.x & 63;
    const int wave_g = blockIdx.x * (THREADS / 64) + (threadIdx.x >> 6);
    const int nwaves = gridDim.x * (THREADS / 64);
    const int chunk = (E + nwaves - 1) / nwaves;
    const int e0 = wave_g * chunk;
    const int e1 = min(e0 + chunk, E);
    for (int e = e0; e < e1; ++e) {
        float v = X[(size_t)e * 64 + lane];
        int r = row_idx[e];
        unsafeAtomicAdd(&acc[(size_t)r * 64 + lane], v);
    }
}

extern "C" void kernel_launch(void* const* d_in, const int* in_sizes, int n_in,
                              void* d_out, int out_size, void* d_ws, size_t ws_size,
                              hipStream_t stream) {
    const float* edge_features = (const float*)d_in[0];
    const int*   edge_index    = (const int*)d_in[1];   // [2, E] int32
    const float* W             = (const float*)d_in[3]; // [64, 64]
    float* out = (float*)d_out;

    const int E = in_sizes[1] / 2;                 // 1,000,000
    const int N = out_size / 64;                   // 50,000 nodes
    const int* row_idx = edge_index;               // edge_index[0]

    // workspace layout: [cnt: N ints][pad to 256B][ids: N*CAP ints]
    const size_t cnt_bytes = ((size_t)N * sizeof(int) + 255) & ~(size_t)255;
    const size_t ids_bytes = (size_t)N * CAP * sizeof(int);
    const bool use_csr = (ws_size >= cnt_bytes + ids_bytes);

    // d_out / d_ws are re-poisoned 0xAA before every timed call.
    hipMemsetAsync(d_out, 0, (size_t)out_size * sizeof(float), stream);

    if (use_csr) {
        int* cnt = (int*)d_ws;
        int* ids = (int*)((char*)d_ws + cnt_bytes);
        hipMemsetAsync(cnt, 0, (size_t)N * sizeof(int), stream);

        bin_kernel<<<(E + THREADS - 1) / THREADS, THREADS, 0, stream>>>(
            row_idx, cnt, ids, edge_features, out, E);
        gather_kernel<<<(N + 3) / 4, THREADS, 0, stream>>>(
            edge_features, ids, cnt, out, N);
    } else {
        scatter_accum_kernel<<<2048, THREADS, 0, stream>>>(edge_features,
                                                           row_idx, out, E);
    }

    project_inplace_kernel<<<(N + 31) / 32, THREADS, 0, stream>>>(out, W, N);
}